// Round 2
// baseline (22937.225 us; speedup 1.0000x reference)
//
#include <hip/hip_runtime.h>
#include <cstdint>
#include <cstddef>

#define HH 128   // hidden
#define II 64    // input
#define OO 64    // output
#define G3 384   // 3*H
#define BB 64    // batch
#define TT 2048  // time
#define GX_ROWS 32

__device__ __forceinline__ float sigf(float x) { return 1.0f / (1.0f + __expf(-x)); }
__device__ __forceinline__ float tanh_fast(float x) {
    x = fminf(20.0f, fmaxf(-20.0f, x));
    float e = __expf(2.0f * x);
    return (e - 1.0f) / (e + 1.0f);
}

// ---------------- gx = x @ W_ih^T + b_ih  (parallel GEMM) ----------------
__global__ __launch_bounds__(384) void gru_gx_kernel(
        const float* __restrict__ x, const float* __restrict__ W_ih,
        const float* __restrict__ b_ih, float* __restrict__ gx) {
    __shared__ __align__(16) float sx[GX_ROWS][II];
    const int g = threadIdx.x;
    const int64_t row0 = (int64_t)blockIdx.x * GX_ROWS;

    float w[II];
#pragma unroll
    for (int k = 0; k < II; ++k) w[k] = W_ih[g * II + k];
    const float bias = b_ih[g];

    for (int i = g; i < GX_ROWS * II; i += 384)
        ((float*)sx)[i] = x[row0 * II + i];
    __syncthreads();

    const float4* sx4 = (const float4*)sx;
#pragma unroll 4
    for (int r = 0; r < GX_ROWS; ++r) {
        float acc = bias;
#pragma unroll
        for (int k4 = 0; k4 < II / 4; ++k4) {
            float4 v = sx4[r * (II / 4) + k4];
            acc += w[4*k4+0]*v.x + w[4*k4+1]*v.y + w[4*k4+2]*v.z + w[4*k4+3]*v.w;
        }
        gx[(row0 + r) * (int64_t)G3 + g] = acc;
    }
}

// ---------------- recurrent scan: one block per batch, 768 threads -------
// Thread tid: row-pair p = tid>>2 (rows 2p, 2p+1), k-chunk c = tid&3
// (k in [32c, 32c+32)). 64 weight floats/thread stay in VGPRs (the R1
// version's 128-float array spilled to scratch: VGPR_Count was 80).
// Partial dots combined across the 4 chunks with shfl_xor(1|2).
__global__ __launch_bounds__(768, 3) void gru_scan_kernel(
        const float* __restrict__ W_hh, const float* __restrict__ b_hh,
        const float* __restrict__ gx, float* __restrict__ hs) {
    __shared__ __align__(16) float sh[HH];
    __shared__ __align__(16) float sC[G3];

    const int b = blockIdx.x;
    const int g = threadIdx.x;
    const int c = g & 3;       // k-chunk
    const int p = g >> 2;      // row pair, 0..191
    const int r0 = 2 * p;
    const int r1 = 2 * p + 1;

    // 2 rows x 32 k of W_hh -> 16 float4 in VGPRs
    float4 w0[8], w1[8];
    {
        const float4* Wr0 = (const float4*)(W_hh + (size_t)r0 * HH + c * 32);
        const float4* Wr1 = (const float4*)(W_hh + (size_t)r1 * HH + c * 32);
#pragma unroll
        for (int i = 0; i < 8; ++i) { w0[i] = Wr0[i]; w1[i] = Wr1[i]; }
    }
    const float bh0 = (c == 0) ? b_hh[r0] : 0.0f;
    const float bh1 = (c == 0) ? b_hh[r1] : 0.0f;

    if (g < HH) sh[g] = 0.0f;
    __syncthreads();

    const float4* sh4 = (const float4*)sh;
    const float* gxb = gx + (size_t)b * TT * G3;
    float* hsb = hs + (size_t)b * TT * HH;

    float g0 = 0, g1 = 0, g2 = 0;
    if (g < HH) { g0 = gxb[g]; g1 = gxb[HH + g]; g2 = gxb[2 * HH + g]; }

    for (int t = 0; t < TT; ++t) {
        // prefetch next step's gx early (hides HBM/L3 latency under matvec)
        float n0 = 0, n1 = 0, n2 = 0;
        if (g < HH && t + 1 < TT) {
            const float* q = gxb + (size_t)(t + 1) * G3;
            n0 = q[g]; n1 = q[HH + g]; n2 = q[2 * HH + g];
        }

        // matvec: rows r0,r1 over k-chunk c. Chunk-staggered LDS reads:
        // slot j -> float4 index (j+2c)&7 within chunk => banks distinct
        // across chunks (at worst 2-way aliasing, which is free).
        float a0e = bh0, a0o = 0.0f, a1e = bh1, a1o = 0.0f;
#pragma unroll
        for (int j = 0; j < 8; j += 2) {
            const int i0 = (j + 2 * c) & 7;
            const int i1 = (j + 1 + 2 * c) & 7;
            const float4 h0 = sh4[c * 8 + i0];
            const float4 h1 = sh4[c * 8 + i1];
            a0e += w0[i0].x*h0.x + w0[i0].y*h0.y + w0[i0].z*h0.z + w0[i0].w*h0.w;
            a1e += w1[i0].x*h0.x + w1[i0].y*h0.y + w1[i0].z*h0.z + w1[i0].w*h0.w;
            a0o += w0[i1].x*h1.x + w0[i1].y*h1.y + w0[i1].z*h1.z + w0[i1].w*h1.w;
            a1o += w1[i1].x*h1.x + w1[i1].y*h1.y + w1[i1].z*h1.z + w1[i1].w*h1.w;
        }
        float a0 = a0e + a0o;
        float a1 = a1e + a1o;
        // combine the 4 k-chunks (lanes 4p..4p+3)
        a0 += __shfl_xor(a0, 1); a0 += __shfl_xor(a0, 2);
        a1 += __shfl_xor(a1, 1); a1 += __shfl_xor(a1, 2);
        if (c == 0) *(float2*)&sC[r0] = make_float2(a0, a1);
        __syncthreads();  // B1: sC complete, all sh reads done

        if (g < HH) {
            float r = sigf(g0 + sC[g]);
            float z = sigf(g1 + sC[HH + g]);
            float n = tanh_fast(g2 + r * sC[2 * HH + g]);
            float hn = (1.0f - z) * n + z * sh[g];
            sh[g] = hn;
            hsb[(size_t)t * HH + g] = hn;
            g0 = n0; g1 = n1; g2 = n2;
        }
        __syncthreads();  // B2: sh updated before next matvec
    }
}

// ---------------- fallback: fully fused scan (if ws too small) -----------
__global__ __launch_bounds__(384, 2) void gru_scan_fused_kernel(
        const float* __restrict__ x, const float* __restrict__ W_ih,
        const float* __restrict__ b_ih, const float* __restrict__ W_hh,
        const float* __restrict__ b_hh, const float* __restrict__ W_out,
        const float* __restrict__ b_out, float* __restrict__ out) {
    __shared__ __align__(16) float sh[HH];
    __shared__ float sC[G3];
    __shared__ float sA[G3];
    __shared__ __align__(16) float sx[II];
    __shared__ __align__(16) float sWq[HH / 4][OO][4];
    __shared__ float sPart[4][OO];

    const int b = blockIdx.x;
    const int g = threadIdx.x;

    float whh[HH];
#pragma unroll
    for (int k = 0; k < HH; ++k) whh[k] = W_hh[g * HH + k];
    const float bh = b_hh[g];
    float wih[II];
#pragma unroll
    for (int k = 0; k < II; ++k) wih[k] = W_ih[g * II + k];
    const float bi = b_ih[g];
    float bo = (g < OO) ? b_out[g] : 0.0f;
    for (int i = g; i < OO * HH; i += 384) {
        int o = i / HH, k = i % HH;
        sWq[k >> 2][o][k & 3] = W_out[i];
    }
    if (g < HH) sh[g] = 0.0f;
    __syncthreads();

    const float4* sh4 = (const float4*)sh;
    const float* xb = x + (size_t)b * TT * II;
    float* outb = out + (size_t)b * TT * OO;
    const float4* sx4 = (const float4*)sx;
    for (int t = 0; t < TT; ++t) {
        if (g < II) sx[g] = xb[(size_t)t * II + g];
        __syncthreads();
        float a = bi, cc = bh;
#pragma unroll
        for (int k4 = 0; k4 < II / 4; ++k4) {
            float4 v = sx4[k4];
            a += wih[4*k4+0]*v.x + wih[4*k4+1]*v.y + wih[4*k4+2]*v.z + wih[4*k4+3]*v.w;
        }
#pragma unroll
        for (int k4 = 0; k4 < HH / 4; ++k4) {
            float4 v = sh4[k4];
            cc += whh[4*k4+0]*v.x + whh[4*k4+1]*v.y + whh[4*k4+2]*v.z + whh[4*k4+3]*v.w;
        }
        sA[g] = a; sC[g] = cc;
        __syncthreads();
        if (g < HH) {
            float r = sigf(sA[g] + sC[g]);
            float z = sigf(sA[HH + g] + sC[HH + g]);
            float n = tanh_fast(sA[2 * HH + g] + r * sC[2 * HH + g]);
            sh[g] = (1.0f - z) * n + z * sh[g];
        }
        __syncthreads();
        if (g < 256) {
            const int o = g & 63, part = g >> 6;
            float s = 0.0f;
#pragma unroll
            for (int k4 = 0; k4 < 8; ++k4) {
                const float4 wv = *(const float4*)sWq[part * 8 + k4][o];
                const float4 hv = sh4[part * 8 + k4];
                s += wv.x*hv.x + wv.y*hv.y + wv.z*hv.z + wv.w*hv.w;
            }
            sPart[part][o] = s;
        }
        __syncthreads();
        if (g < OO)
            outb[(size_t)t * OO + g] =
                bo + sPart[0][g] + sPart[1][g] + sPart[2][g] + sPart[3][g];
    }
}

// ---------------- out = hs @ W_out^T + b_out (parallel GEMM) -------------
__global__ __launch_bounds__(256) void gru_outproj_kernel(
        const float* __restrict__ hs, const float* __restrict__ W_out,
        const float* __restrict__ b_out, float* __restrict__ out) {
    __shared__ __align__(16) float sW[HH / 4][OO][4];
    __shared__ float sb[OO];
    const int tid = threadIdx.x;
    for (int i = tid; i < OO * HH; i += 256) {
        int o = i / HH, k = i % HH;
        sW[k >> 2][o][k & 3] = W_out[i];
    }
    if (tid < OO) sb[tid] = b_out[tid];
    __syncthreads();

    const int64_t row = (int64_t)blockIdx.x * 256 + tid;
    const float4* hrow = (const float4*)(hs + row * HH);
    float acc[OO];
#pragma unroll
    for (int o = 0; o < OO; ++o) acc[o] = 0.0f;
    for (int k4 = 0; k4 < HH / 4; ++k4) {
        float4 h4 = hrow[k4];
#pragma unroll
        for (int o = 0; o < OO; ++o) {
            const float4 w = *(const float4*)sW[k4][o];
            acc[o] += w.x*h4.x + w.y*h4.y + w.z*h4.z + w.w*h4.w;
        }
    }
    float* orow = out + row * OO;
#pragma unroll
    for (int o = 0; o < OO; ++o) orow[o] = sb[o] + acc[o];
}

extern "C" void kernel_launch(void* const* d_in, const int* in_sizes, int n_in,
                              void* d_out, int out_size, void* d_ws, size_t ws_size,
                              hipStream_t stream) {
    const float* x     = (const float*)d_in[0];
    const float* W_ih  = (const float*)d_in[1];
    const float* W_hh  = (const float*)d_in[2];
    const float* b_ih  = (const float*)d_in[3];
    const float* b_hh  = (const float*)d_in[4];
    const float* W_out = (const float*)d_in[5];
    const float* b_out = (const float*)d_in[6];
    float* out = (float*)d_out;

    const size_t need_gx = (size_t)BB * TT * G3 * sizeof(float);  // 201 MB
    const size_t need_hs = (size_t)BB * TT * HH * sizeof(float);  //  67 MB

    if (ws_size >= need_gx + need_hs) {
        float* gx = (float*)d_ws;
        float* hs = (float*)((char*)d_ws + need_gx);
        gru_gx_kernel<<<(BB * TT) / GX_ROWS, 384, 0, stream>>>(x, W_ih, b_ih, gx);
        gru_scan_kernel<<<BB, 768, 0, stream>>>(W_hh, b_hh, gx, hs);
        gru_outproj_kernel<<<(BB * TT) / 256, 256, 0, stream>>>(hs, W_out, b_out, out);
    } else {
        gru_scan_fused_kernel<<<BB, 384, 0, stream>>>(
            x, W_ih, b_ih, W_hh, b_hh, W_out, b_out, out);
    }
}

// Round 3
// 1740.710 us; speedup vs baseline: 13.1769x; 13.1769x over previous
//
#include <hip/hip_runtime.h>
#include <cstdint>
#include <cstddef>

#define HH 128   // hidden
#define II 64    // input
#define OO 64    // output
#define G3 384   // 3*H
#define BB 64    // batch
#define TT 2048  // time
#define GX_ROWS 32

__device__ __forceinline__ float sigf(float x) { return 1.0f / (1.0f + __expf(-x)); }
__device__ __forceinline__ float tanh_fast(float x) {
    x = fminf(20.0f, fmaxf(-20.0f, x));
    float e = __expf(2.0f * x);
    return (e - 1.0f) / (e + 1.0f);
}
__device__ __forceinline__ float dot4(float4 a, float4 b) {
    return a.x * b.x + a.y * b.y + a.z * b.z + a.w * b.w;
}

// ---------------- gx = x @ W_ih^T + b_ih  (parallel GEMM) ----------------
// 768 threads: gate-row g = tid>>1, k-half kh = tid&1 (32 weights/thread ->
// guaranteed register-resident). Pair combined with shfl_xor(1).
__global__ __launch_bounds__(768) void gru_gx_kernel(
        const float* __restrict__ x, const float* __restrict__ W_ih,
        const float* __restrict__ b_ih, float* __restrict__ gx) {
    __shared__ __align__(16) float sx[GX_ROWS][II];
    const int tid = threadIdx.x;
    const int g = tid >> 1;
    const int kh = tid & 1;
    const int64_t row0 = (int64_t)blockIdx.x * GX_ROWS;

    float4 w4[8];
    {
        const float4* Wp = (const float4*)(W_ih + (size_t)g * II + kh * 32);
#pragma unroll
        for (int i = 0; i < 8; ++i) w4[i] = Wp[i];
    }
    const float bias = b_ih[g];

    for (int i = tid; i < GX_ROWS * II; i += 768)
        ((float*)sx)[i] = x[row0 * II + i];
    __syncthreads();

#pragma unroll 4
    for (int r = 0; r < GX_ROWS; ++r) {
        const float4* sx4 = (const float4*)sx[r] + kh * 8;
        float acc = 0.0f;
#pragma unroll
        for (int i = 0; i < 8; ++i) acc += dot4(w4[i], sx4[i]);
        acc += __shfl_xor(acc, 1);
        if (kh == 0) gx[(row0 + r) * (int64_t)G3 + g] = acc + bias;
    }
}

// ---------------- recurrent scan: one block per batch, 768 threads -------
// Thread tid: row-pair p = tid>>2 (rows 2p,2p+1), k-chunk c = tid&3.
// Weights PRE-ROTATED at load: w0[j] = Wrow[(j+2c)&7] so ALL register-array
// indices in the hot loop are compile-time static (R2's runtime index sent
// the arrays to scratch: VGPR_Count=40, 10x regression). LDS reads keep the
// rotation -> 4 unique addrs per ds_read_b128 on 16 distinct banks
// (16-lane broadcast groups, conflict-free).
__global__ __launch_bounds__(768, 3) void gru_scan_kernel(
        const float* __restrict__ W_hh, const float* __restrict__ b_hh,
        const float* __restrict__ gx, float* __restrict__ hs) {
    __shared__ __align__(16) float sh[HH];
    __shared__ __align__(16) float sC[G3];

    const int b = blockIdx.x;
    const int g = threadIdx.x;
    const int c = g & 3;       // k-chunk
    const int p = g >> 2;      // row pair, 0..191
    const int r0 = 2 * p;
    const int r1 = 2 * p + 1;

    float4 w0[8], w1[8];
    {
        const float4* Wr0 = (const float4*)(W_hh + (size_t)r0 * HH + c * 32);
        const float4* Wr1 = (const float4*)(W_hh + (size_t)r1 * HH + c * 32);
#pragma unroll
        for (int j = 0; j < 8; ++j) {
            const int idx = (j + 2 * c) & 7;   // runtime -> global ADDRESS only
            w0[j] = Wr0[idx];
            w1[j] = Wr1[idx];
        }
    }
    const float bh0 = (c == 0) ? b_hh[r0] : 0.0f;
    const float bh1 = (c == 0) ? b_hh[r1] : 0.0f;

    if (g < HH) sh[g] = 0.0f;
    __syncthreads();

    const float4* shc = (const float4*)sh + c * 8;
    const float* gxb = gx + (size_t)b * TT * G3;
    float* hsb = hs + (size_t)b * TT * HH;

    float g0 = 0, g1 = 0, g2 = 0;
    if (g < HH) { g0 = gxb[g]; g1 = gxb[HH + g]; g2 = gxb[2 * HH + g]; }

    for (int t = 0; t < TT; ++t) {
        // prefetch next step's gx early (hides L2/HBM latency under matvec)
        float n0 = 0, n1 = 0, n2 = 0;
        if (g < HH && t + 1 < TT) {
            const float* q = gxb + (size_t)(t + 1) * G3;
            n0 = q[g]; n1 = q[HH + g]; n2 = q[2 * HH + g];
        }

        float a0e = bh0, a0o = 0.0f, a1e = bh1, a1o = 0.0f;
#pragma unroll
        for (int j = 0; j < 8; j += 2) {
            const int i0 = (j + 2 * c) & 7;       // LDS address only
            const int i1 = (j + 1 + 2 * c) & 7;
            const float4 h0 = shc[i0];
            const float4 h1 = shc[i1];
            a0e += dot4(w0[j], h0);               // static reg-array indices
            a1e += dot4(w1[j], h0);
            a0o += dot4(w0[j + 1], h1);
            a1o += dot4(w1[j + 1], h1);
        }
        float a0 = a0e + a0o;
        float a1 = a1e + a1o;
        a0 += __shfl_xor(a0, 1); a0 += __shfl_xor(a0, 2);
        a1 += __shfl_xor(a1, 1); a1 += __shfl_xor(a1, 2);
        if (c == 0) *(float2*)&sC[r0] = make_float2(a0, a1);
        __syncthreads();  // B1: sC complete, all sh reads done

        if (g < HH) {
            float r = sigf(g0 + sC[g]);
            float z = sigf(g1 + sC[HH + g]);
            float n = tanh_fast(g2 + r * sC[2 * HH + g]);
            float hn = (1.0f - z) * n + z * sh[g];
            sh[g] = hn;
            hsb[(size_t)t * HH + g] = hn;
            g0 = n0; g1 = n1; g2 = n2;
        }
        __syncthreads();  // B2: sh updated before next matvec
    }
}

// ---------------- fallback: fully fused scan (if ws too small) -----------
__global__ __launch_bounds__(384, 2) void gru_scan_fused_kernel(
        const float* __restrict__ x, const float* __restrict__ W_ih,
        const float* __restrict__ b_ih, const float* __restrict__ W_hh,
        const float* __restrict__ b_hh, const float* __restrict__ W_out,
        const float* __restrict__ b_out, float* __restrict__ out) {
    __shared__ __align__(16) float sh[HH];
    __shared__ float sC[G3];
    __shared__ float sA[G3];
    __shared__ __align__(16) float sx[II];
    __shared__ __align__(16) float sWq[HH / 4][OO][4];
    __shared__ float sPart[4][OO];

    const int b = blockIdx.x;
    const int g = threadIdx.x;

    float whh[HH];
#pragma unroll
    for (int k = 0; k < HH; ++k) whh[k] = W_hh[g * HH + k];
    const float bh = b_hh[g];
    float wih[II];
#pragma unroll
    for (int k = 0; k < II; ++k) wih[k] = W_ih[g * II + k];
    const float bi = b_ih[g];
    float bo = (g < OO) ? b_out[g] : 0.0f;
    for (int i = g; i < OO * HH; i += 384) {
        int o = i / HH, k = i % HH;
        sWq[k >> 2][o][k & 3] = W_out[i];
    }
    if (g < HH) sh[g] = 0.0f;
    __syncthreads();

    const float4* sh4 = (const float4*)sh;
    const float* xb = x + (size_t)b * TT * II;
    float* outb = out + (size_t)b * TT * OO;
    const float4* sx4 = (const float4*)sx;
    for (int t = 0; t < TT; ++t) {
        if (g < II) sx[g] = xb[(size_t)t * II + g];
        __syncthreads();
        float a = bi, cc = bh;
#pragma unroll
        for (int k4 = 0; k4 < II / 4; ++k4) {
            float4 v = sx4[k4];
            a += wih[4*k4+0]*v.x + wih[4*k4+1]*v.y + wih[4*k4+2]*v.z + wih[4*k4+3]*v.w;
        }
#pragma unroll
        for (int k4 = 0; k4 < HH / 4; ++k4) {
            float4 v = sh4[k4];
            cc += whh[4*k4+0]*v.x + whh[4*k4+1]*v.y + whh[4*k4+2]*v.z + whh[4*k4+3]*v.w;
        }
        sA[g] = a; sC[g] = cc;
        __syncthreads();
        if (g < HH) {
            float r = sigf(sA[g] + sC[g]);
            float z = sigf(sA[HH + g] + sC[HH + g]);
            float n = tanh_fast(sA[2 * HH + g] + r * sC[2 * HH + g]);
            sh[g] = (1.0f - z) * n + z * sh[g];
        }
        __syncthreads();
        if (g < 256) {
            const int o = g & 63, part = g >> 6;
            float s = 0.0f;
#pragma unroll
            for (int k4 = 0; k4 < 8; ++k4) {
                const float4 wv = *(const float4*)sWq[part * 8 + k4][o];
                const float4 hv = sh4[part * 8 + k4];
                s += wv.x*hv.x + wv.y*hv.y + wv.z*hv.z + wv.w*hv.w;
            }
            sPart[part][o] = s;
        }
        __syncthreads();
        if (g < OO)
            outb[(size_t)t * OO + g] =
                bo + sPart[0][g] + sPart[1][g] + sPart[2][g] + sPart[3][g];
    }
}

// ---------------- out = hs @ W_out^T + b_out (parallel GEMM) -------------
__global__ __launch_bounds__(256) void gru_outproj_kernel(
        const float* __restrict__ hs, const float* __restrict__ W_out,
        const float* __restrict__ b_out, float* __restrict__ out) {
    __shared__ __align__(16) float sW[HH / 4][OO][4];
    __shared__ float sb[OO];
    const int tid = threadIdx.x;
    for (int i = tid; i < OO * HH; i += 256) {
        int o = i / HH, k = i % HH;
        sW[k >> 2][o][k & 3] = W_out[i];
    }
    if (tid < OO) sb[tid] = b_out[tid];
    __syncthreads();

    const int64_t row = (int64_t)blockIdx.x * 256 + tid;
    const float4* hrow = (const float4*)(hs + row * HH);
    float acc[OO];
#pragma unroll
    for (int o = 0; o < OO; ++o) acc[o] = 0.0f;
    for (int k4 = 0; k4 < HH / 4; ++k4) {
        float4 h4 = hrow[k4];
#pragma unroll
        for (int o = 0; o < OO; ++o) {
            const float4 w = *(const float4*)sW[k4][o];
            acc[o] += w.x*h4.x + w.y*h4.y + w.z*h4.z + w.w*h4.w;
        }
    }
    float* orow = out + row * OO;
#pragma unroll
    for (int o = 0; o < OO; ++o) orow[o] = sb[o] + acc[o];
}

extern "C" void kernel_launch(void* const* d_in, const int* in_sizes, int n_in,
                              void* d_out, int out_size, void* d_ws, size_t ws_size,
                              hipStream_t stream) {
    const float* x     = (const float*)d_in[0];
    const float* W_ih  = (const float*)d_in[1];
    const float* W_hh  = (const float*)d_in[2];
    const float* b_ih  = (const float*)d_in[3];
    const float* b_hh  = (const float*)d_in[4];
    const float* W_out = (const float*)d_in[5];
    const float* b_out = (const float*)d_in[6];
    float* out = (float*)d_out;

    const size_t need_gx = (size_t)BB * TT * G3 * sizeof(float);  // 201 MB
    const size_t need_hs = (size_t)BB * TT * HH * sizeof(float);  //  67 MB

    if (ws_size >= need_gx + need_hs) {
        float* gx = (float*)d_ws;
        float* hs = (float*)((char*)d_ws + need_gx);
        gru_gx_kernel<<<(BB * TT) / GX_ROWS, 768, 0, stream>>>(x, W_ih, b_ih, gx);
        gru_scan_kernel<<<BB, 768, 0, stream>>>(W_hh, b_hh, gx, hs);
        gru_outproj_kernel<<<(BB * TT) / 256, 256, 0, stream>>>(hs, W_out, b_out, out);
    } else {
        gru_scan_fused_kernel<<<BB, 384, 0, stream>>>(
            x, W_ih, b_ih, W_hh, b_hh, W_out, b_out, out);
    }
}